// Round 6
// baseline (387.927 us; speedup 1.0000x reference)
//
#include <hip/hip_runtime.h>

// Problem constants (ConvHex): B=256, C_IN=64, C_OUT=128, H=1039, K=6
// Dtypes: x, weights, bias, out = fp32; neighbors = int32.
// Compute uses bf16 MFMA; threshold 3.375e-2 covers bf16 rounding (measured 7.8e-3).
//
// Design (round 6): one block per batch, 768 threads (12 waves = 3/SIMD).
// x[b] transposed straight into LDS (bf16, XOR-swizzled 128B rows, 1040 rows
// = 130 KB); 22 48-h tiles computed from LDS in place via gathered
// ds_read_b128 (neighbors are batch-local).
// Round-6 changes (ILP, not occupancy):
//  - __launch_bounds__(768, 3): rounds 4/5 allocated 84 VGPR (compiler
//    targeted 6 waves/SIMD -- unreachable with 130KB LDS) and serialized the
//    gather->MFMA chain into ~14 exposed LDS round-trips per tile.
//  - all 14 B-frags batch-loaded into a static reg array before the MFMA
//    chain (gathers pipeline on the LDS pipe instead of round-tripping).
//  - tile-index math (voff/inv) software-pipelined one tile ahead; nb loads
//    issued two tiles ahead (named double buffers, all static indexing).
#define BATCH 256
#define CIN   64
#define COUT  128
#define HEX   1039
#define KNB   6
#define ZROW  HEX              // zero row index in LDS (gather target for pads)
#define TILEH 48               // h per tile (12 waves = 4 m-pairs x 3 h16s)
#define NTILE 22               // ceil(HEX / TILEH)
#define LDSB  ((HEX + 1) * 128)   // 1040 rows * 128 B = 133120 B

typedef __attribute__((ext_vector_type(8))) short bf16x8;   // 8 bf16 = 4 VGPRs
typedef __attribute__((ext_vector_type(4))) float f32x4;

__device__ __forceinline__ unsigned short f2bf(float f) {
    unsigned int u = __builtin_bit_cast(unsigned int, f);
    u += 0x7fffu + ((u >> 16) & 1);          // RTNE
    return (unsigned short)(u >> 16);
}

// ---------------------------------------------------------------------------
// k_prep: pack [Wc|Wn] fp32 -> wf bf16 in MFMA A-fragment lane order.
// wf element e = ((kb*8 + mt)*64 + lane)*8 + j :
//   o = mt*16 + (lane&15); kd = kb*32 + (lane>>4)*8 + j = jn*64 + c
__global__ __launch_bounds__(256) void k_prep(const float* __restrict__ wc,
                                              const float* __restrict__ wn,
                                              unsigned short* __restrict__ wf) {
    int e    = blockIdx.x * 256 + threadIdx.x;   // 0 .. 57343
    int j    = e & 7;
    int lane = (e >> 3) & 63;
    int mt   = (e >> 9) & 7;
    int kb   = e >> 12;                          // 0..13
    int o  = mt * 16 + (lane & 15);
    int kd = kb * 32 + (lane >> 4) * 8 + j;
    int jn = kd >> 6;
    int c  = kd & 63;
    float v = (jn == 0) ? wc[o * CIN + c]
                        : wn[(o * CIN + c) * KNB + (jn - 1)];
    wf[e] = f2bf(v);
}

// ---------------------------------------------------------------------------
// k_main: block = batch. 768 threads = 12 waves = 4 m-pairs x 3 h16s.
// Phase 1: transpose x[b][c][h] -> LDS row h (64 bf16, swizzled chunks).
//   Row layout: byte(h, chunk q) = h*128 + ((q ^ (h&7))<<4). Rows are 128B =
//   exactly 32 banks, so the bank pattern depends only on the chunk slot; the
//   XOR keeps the phase-1 b128 writes bijective and the phase-2 gathered b128
//   reads (random rows -> near-uniform slots) bank-balanced.
// Phase 2: per tile ht, wave (m,hq) computes o in [32m,32m+32) x 16 h.
//   B-frags gathered from LDS by per-lane row index (center / nb / ZROW);
//   A-fragments streamed from wf (L1/L2); 28 MFMA per wave per tile; no
//   barriers after the single post-transpose one.

// issue the 6 neighbor-index loads for tile HT2 into array R (static idx)
#define LOADRAW(HT2, R)                                              \
    if ((HT2) < NTILE) {                                             \
        int h2_ = (HT2) * TILEH + ho;                                \
        int hs_ = (h2_ < HEX) ? h2_ : 0;                             \
        _Pragma("unroll")                                            \
        for (int j = 0; j < KNB; ++j) R[j] = nb[hs_ * KNB + j];      \
    }

// turn raw indices R of tile T into LDS byte offsets V + 1/count INV
#define MAKEVOFF(T, R, V, INV)                                       \
    if ((T) < NTILE) {                                               \
        int h2_ = (T) * TILEH + ho;                                  \
        bool hv_ = (h2_ < HEX);                                      \
        V[0] = offg(hv_ ? h2_ : ZROW);                               \
        int cnt_ = 1;                                                \
        _Pragma("unroll")                                            \
        for (int j = 0; j < KNB; ++j) {                              \
            int t2_ = R[j];                                          \
            bool val_ = hv_ && (t2_ >= 0);                           \
            cnt_ += val_ ? 1 : 0;                                    \
            V[j + 1] = offg(val_ ? t2_ : ZROW);                      \
        }                                                            \
        INV = 1.0f / (float)cnt_;                                    \
    }

// one tile: batch-gather 14 B-frags, prep next tile's voff, issue nb loads
// two tiles ahead, MFMA chain, epilogue.
#define TILE_STEP(HT, V, INV, RN, VN, INVN, RL)                      \
    {                                                                \
        bf16x8 bb[14];                                               \
        _Pragma("unroll")                                            \
        for (int ks = 0; ks < 14; ++ks)                              \
            bb[ks] = *(const bf16x8*)((const char*)XT +              \
                        (V[ks >> 1] ^ ((ks & 1) << 6)));             \
        MAKEVOFF((HT) + 1, RN, VN, INVN);                            \
        LOADRAW((HT) + 2, RL);                                       \
        f32x4 acc0 = {}, acc1 = {};                                  \
        _Pragma("unroll")                                            \
        for (int ks = 0; ks < 14; ++ks) {                            \
            acc0 = __builtin_amdgcn_mfma_f32_16x16x32_bf16(          \
                wfv[(ks * 8 + 2 * m + 0) * 64 + lane], bb[ks], acc0, 0, 0, 0); \
            acc1 = __builtin_amdgcn_mfma_f32_16x16x32_bf16(          \
                wfv[(ks * 8 + 2 * m + 1) * 64 + lane], bb[ks], acc1, 0, 0, 0); \
        }                                                            \
        int he_ = (HT) * TILEH + ho;                                 \
        if (he_ < HEX) {                                             \
            _Pragma("unroll")                                        \
            for (int r = 0; r < 4; ++r) {                            \
                int o0_ = (2 * m + 0) * 16 + quad * 4 + r;           \
                outb[(size_t)o0_ * HEX + he_] = acc0[r] * (INV) + bs[0][r]; \
                int o1_ = (2 * m + 1) * 16 + quad * 4 + r;           \
                outb[(size_t)o1_ * HEX + he_] = acc1[r] * (INV) + bs[1][r]; \
            }                                                        \
        }                                                            \
    }

__global__ __launch_bounds__(768, 3) void k_main(const float* __restrict__ x,
                                                 const int* __restrict__ nb,
                                                 const unsigned short* __restrict__ wf,
                                                 const float* __restrict__ bias,
                                                 float* __restrict__ out) {
    extern __shared__ __align__(16) unsigned short XT[];   // [1040 rows][128 B]

    int b    = blockIdx.x;
    int tid  = threadIdx.x;
    int lane = tid & 63;
    int wv   = tid >> 6;                 // 0..11
    int quad = lane >> 4;
    int l16  = lane & 15;
    int m    = wv & 3;                   // m-pair: o-tiles {2m, 2m+1}
    int hq   = wv >> 2;                  // h sixteenth 0..2

    const bf16x8* wfv = (const bf16x8*)wf;

    float bs[2][4];
    #pragma unroll
    for (int mi = 0; mi < 2; ++mi)
        #pragma unroll
        for (int r = 0; r < 4; ++r)
            bs[mi][r] = bias[(2 * m + mi) * 16 + quad * 4 + r];

    // ---- phase 1: transpose into LDS. Task e = h*8 + cc (1040*8 = 8320).
    // Per task: 8 strided 4B loads (wave: 8 c-rows x 32B segments, each line
    // consumed once by the block) -> one swizzled b128 LDS write.
    {
        const float* xb = x + (size_t)b * (CIN * HEX);
        #pragma unroll 1
        for (int t = 0; t < 11; ++t) {
            int e = t * 768 + tid;
            if (e < 8320) {
                int h  = e >> 3;
                int cc = e & 7;
                bf16x8 v = {};
                if (h < HEX) {
                    #pragma unroll
                    for (int k = 0; k < 8; ++k)
                        v[k] = (short)f2bf(xb[(size_t)(cc * 8 + k) * HEX + h]);
                }
                *(bf16x8*)((char*)XT + h * 128 + ((cc ^ (h & 7)) << 4)) = v;
            }
        }
    }
    __syncthreads();

    // ---- phase 2: 22 tiles, software-pipelined, no barriers.
    int ho = hq * 16 + l16;                  // h = ht*TILEH + ho
    // byte offset of (row g, chunk quad) with swizzle; ks-odd XORs bit 6.
    auto offg = [&](int g) { return (g << 7) | ((quad ^ (g & 7)) << 4); };

    float* outb = out + (size_t)b * ((size_t)COUT * HEX);

    int rawnA[6], rawnB[6];
    int voffC[7], voffN[7];
    float invC = 1.0f, invN = 1.0f;

    LOADRAW(0, rawnA);
    MAKEVOFF(0, rawnA, voffC, invC);
    LOADRAW(1, rawnB);

    #pragma unroll 1
    for (int i = 0; i < NTILE / 2; ++i) {
        int ht = 2 * i;
        TILE_STEP(ht,     voffC, invC, rawnB, voffN, invN, rawnA);
        TILE_STEP(ht + 1, voffN, invN, rawnA, voffC, invC, rawnB);
    }
}

// ---------------------------------------------------------------------------
extern "C" void kernel_launch(void* const* d_in, const int* in_sizes, int n_in,
                              void* d_out, int out_size, void* d_ws, size_t ws_size,
                              hipStream_t stream) {
    const float* x    = (const float*)d_in[0];   // [256][64][1039] fp32
    const int*   nb   = (const int*)d_in[1];     // [1039][6] int32
    const float* wc   = (const float*)d_in[2];   // [128][64] fp32
    const float* wn   = (const float*)d_in[3];   // [128][64][6] fp32
    const float* bias = (const float*)d_in[4];   // [128] fp32
    float*       out  = (float*)d_out;           // [256][128][1039] fp32

    unsigned short* wf = (unsigned short*)d_ws;  // 114688 B of workspace

    static bool s_attr_done = false;
    if (!s_attr_done) {                          // host-side, graph-safe, once
        hipFuncSetAttribute((const void*)k_main,
                            hipFuncAttributeMaxDynamicSharedMemorySize, LDSB);
        s_attr_done = true;
    }

    hipLaunchKernelGGL(k_prep, dim3(224),   dim3(256), 0,    stream, wc, wn, wf);
    hipLaunchKernelGGL(k_main, dim3(BATCH), dim3(768), LDSB, stream,
                       x, nb, wf, bias, out);
}